// Round 7
// baseline (291.013 us; speedup 1.0000x reference)
//
#include <hip/hip_runtime.h>

typedef unsigned short u16;
typedef __bf16 bf16x8 __attribute__((ext_vector_type(8)));
typedef float    f32x4 __attribute__((ext_vector_type(4)));
typedef unsigned short u16x8 __attribute__((ext_vector_type(8)));

__device__ __forceinline__ float bf2f(u16 v){ return __uint_as_float(((unsigned int)v) << 16); }
__device__ __forceinline__ u16 f2bf(float f){
    unsigned int u = __float_as_uint(f);
    u += 0x7fffu + ((u >> 16) & 1u);
    return (u16)(u >> 16);
}
// truncating bf16 (~2^-8 rel err, rounds toward zero); selects d16_hi stores
__device__ __forceinline__ u16 f2bf_t(float f){ return (u16)(__float_as_uint(f) >> 16); }
// pack hi16 of two floats: result = [lo.hi16, hi.hi16]
__device__ __forceinline__ unsigned pack_trunc(float hi, float lo){
    return __builtin_amdgcn_perm(__float_as_uint(hi), __float_as_uint(lo), 0x07060302);
}
// raw v_exp_f32 (no libm denorm fixup); x=-1e30 -> 0
__device__ __forceinline__ float exp2_fast(float x){
    float r; asm("v_exp_f32 %0, %1" : "=v"(r) : "v"(x)); return r;
}

// async global->LDS, 16B per lane; LDS dest = wave-uniform base + lane*16.
__device__ __forceinline__ void glds16(const u16* gp, u16* lp){
    __builtin_amdgcn_global_load_lds((unsigned int __attribute__((address_space(1)))*)gp,
                                     (unsigned int __attribute__((address_space(3)))*)lp,
                                     16, 0, 0);
}

// Wave-uniform input-dtype probe (verified R4-R7).
__device__ __forceinline__ int probe_f32(const u16* __restrict__ xp){
    u16 lo = xp[2 * (threadIdx.x & 63)];
    int e = (lo >> 7) & 0xff;
    bool bad = !(e == 0 || (e > 96 && e < 160));
    return __popcll(__ballot(bad)) > 16;
}

// ---------- x -> canonical bf16 (into d_out scratch) ----------
__global__ __launch_bounds__(256) void conv_x(const void* __restrict__ src, u16* __restrict__ dst,
                                              const u16* __restrict__ xprobe){
    const int isf32 = probe_f32(xprobe);
    size_t i = ((size_t)blockIdx.x * 256 + threadIdx.x) * 8;
    if (isf32){
        const float* p = (const float*)src + i;
        float4 a = *(const float4*)p, b = *(const float4*)(p + 4);
        u16x8 o = { f2bf(a.x), f2bf(a.y), f2bf(a.z), f2bf(a.w),
                    f2bf(b.x), f2bf(b.y), f2bf(b.z), f2bf(b.w) };
        *(u16x8*)(dst + i) = o;
    } else {
        *(u16x8*)(dst + i) = *(const u16x8*)((const u16*)src + i);
    }
}

// ---------- transpose+convert: out[C][R](bf16) = in[R][C](f32 or bf16) ----------
__global__ __launch_bounds__(256) void transposeW(const void* __restrict__ in, u16* __restrict__ out,
                                                  int R, int C, const u16* __restrict__ xprobe){
    __shared__ u16 t[64][65];
    const int isf32 = probe_f32(xprobe);
    const int c0 = blockIdx.x * 64, r0 = blockIdx.y * 64;
    const int tx = threadIdx.x & 15, ty = threadIdx.x >> 4;
#pragma unroll
    for (int i = 0; i < 4; i++){
        int r = ty + i * 16;
        u16 a, b, c, d;
        if (isf32){
            float4 v = *(const float4*)((const float*)in + (size_t)(r0 + r) * C + c0 + tx * 4);
            a = f2bf(v.x); b = f2bf(v.y); c = f2bf(v.z); d = f2bf(v.w);
        } else {
            ushort4 v = *(const ushort4*)((const u16*)in + (size_t)(r0 + r) * C + c0 + tx * 4);
            a = v.x; b = v.y; c = v.z; d = v.w;
        }
        t[r][tx*4+0] = a; t[r][tx*4+1] = b; t[r][tx*4+2] = c; t[r][tx*4+3] = d;
    }
    __syncthreads();
#pragma unroll
    for (int i = 0; i < 4; i++){
        int oc = ty + i * 16;
        ushort4 v;
        v.x = t[tx*4+0][oc]; v.y = t[tx*4+1][oc]; v.z = t[tx*4+2][oc]; v.w = t[tx*4+3][oc];
        *(ushort4*)(out + (size_t)(c0 + oc) * R + r0 + tx * 4) = v;
    }
}

// ---------------- GEMM (m97 structure, BK=64): C[M,N] = A[M,K] @ Bt[N,K]^T + bias --------
// 256 threads = 4 waves (2Mx2N), wave tile 64x64, tile 128x128, single-buffered staging.
// Measured-best R5 configuration (67.5 us on QKV; R6's BK=32 3-slot pipeline regressed):
//  - BK=64 (16 iters, 32 MFMA per drain), LDS union staging|Ct = 34 KiB -> 4 blocks/CU.
//  - bank swizzle on 128B rows: chunk ^= (row&7), pre-swizzled GLOBAL source (rule #21).
//  - T1 bijective XCD swizzle (grid % 8 == 0).
// MODE 0: LDS-restaged epilogue -> coalesced 16B stores to Q(pre-scaled)/K ([bh][t][64])
//         and Vt ([bh][d][2048], V-blocks transposed in LDS).
// MODE 1: C row-major, f32 or bf16 per probe.
#define CTS 136
template<int MODE>
__global__ __launch_bounds__(256) void gemm128(
    const u16* __restrict__ A, const u16* __restrict__ Bt, const void* __restrict__ bias,
    void* __restrict__ C, u16* __restrict__ Cq, u16* __restrict__ Ck, u16* __restrict__ Cv,
    const u16* __restrict__ xprobe, int M, int N, int K)
{
    __shared__ u16 lds[17408];           // union: staging 16384 elems | Ct 128*136
    u16* Asm = lds;                      // [128][64]
    u16* Bsm = lds + 8192;               // [128][64]
    u16* Ct  = lds;                      // epilogue restage (after sync)
    const int isf32 = probe_f32(xprobe);
    const int tid = threadIdx.x;
    const int wave = tid >> 6, lane = tid & 63;
    const int quad = lane >> 4, ml = lane & 15;

    // T1: bijective XCD swizzle (nwg % 8 == 0 for all dispatches)
    const int nbx = gridDim.x;
    int flat = blockIdx.y * nbx + blockIdx.x;
    const int cpx = (nbx * gridDim.y) >> 3;
    flat = (flat & 7) * cpx + (flat >> 3);
    const int m_blk = (flat / nbx) * 128;
    const int n_blk = (flat % nbx) * 128;

    const int wm = (wave >> 1) * 64, wn = (wave & 1) * 64;
    const int srow = lane >> 3;          // 0..7 within the 8-row group
    const int sch  = lane & 7;           // linear dest chunk

    f32x4 acc[4][4];
#pragma unroll
    for (int a = 0; a < 4; a++)
#pragma unroll
        for (int b = 0; b < 4; b++)
            acc[a][b] = (f32x4){0.f, 0.f, 0.f, 0.f};

    for (int k0 = 0; k0 < K; k0 += 64){
        __syncthreads();
#pragma unroll
        for (int i = 0; i < 4; i++){
            int row = wave * 32 + i * 8 + srow;          // 0..127
            int sc  = sch ^ (row & 7);                   // pre-swizzled source chunk
            glds16(A  + (size_t)(m_blk + row) * K + k0 + sc * 8, Asm + (wave * 32 + i * 8) * 64);
            glds16(Bt + (size_t)(n_blk + row) * K + k0 + sc * 8, Bsm + (wave * 32 + i * 8) * 64);
        }
        __syncthreads();
#pragma unroll
        for (int ks = 0; ks < 2; ks++){
            bf16x8 af[4], bfr[4];
#pragma unroll
            for (int mt = 0; mt < 4; mt++)
                af[mt]  = *(const bf16x8*)&Asm[(wm + mt * 16 + ml) * 64 + ((ks * 4 + quad) ^ (ml & 7)) * 8];
#pragma unroll
            for (int nt = 0; nt < 4; nt++)
                bfr[nt] = *(const bf16x8*)&Bsm[(wn + nt * 16 + ml) * 64 + ((ks * 4 + quad) ^ (ml & 7)) * 8];
#pragma unroll
            for (int mt = 0; mt < 4; mt++)
#pragma unroll
                for (int nt = 0; nt < 4; nt++)
                    acc[mt][nt] = __builtin_amdgcn_mfma_f32_16x16x32_bf16(af[mt], bfr[nt], acc[mt][nt], 0, 0, 0);
        }
    }
    __syncthreads();                      // fence: staging LDS -> Ct reuse

    const float QSC = 0.18033688f;   // 0.125 * log2(e) folded into Q
    if (MODE == 0){
        const int which = n_blk >> 10;
        const int hbase = (n_blk >> 6) & 15;
        if (which < 2){
            const float sc = (which == 0) ? QSC : 1.0f;
#pragma unroll
            for (int nt = 0; nt < 4; nt++){
                int col = wn + nt * 16 + ml;
                float bv = isf32 ? ((const float*)bias)[n_blk + col] : bf2f(((const u16*)bias)[n_blk + col]);
#pragma unroll
                for (int mt = 0; mt < 4; mt++){
                    int row0 = wm + mt * 16 + quad * 4;
#pragma unroll
                    for (int r = 0; r < 4; r++)
                        Ct[(row0 + r) * CTS + col] = f2bf_t((acc[mt][nt][r] + bv) * sc);
                }
            }
            __syncthreads();
            u16* dst0 = (which == 0) ? Cq : Ck;
            const int b = m_blk >> 11, t0 = m_blk & 2047;
#pragma unroll
            for (int i = 0; i < 8; i++){
                int u = i * 256 + tid;
                int row = u >> 4, c8 = u & 15;
                int h = hbase + (c8 >> 3), d8 = (c8 & 7) * 8;
                u16x8 v = *(const u16x8*)&Ct[row * CTS + c8 * 8];
                *(u16x8*)&dst0[(((size_t)(b * 16 + h)) * 2048 + (t0 + row)) * 64 + d8] = v;
            }
        } else {
#pragma unroll
            for (int nt = 0; nt < 4; nt++){
                int col = wn + nt * 16 + ml;
                float bv = isf32 ? ((const float*)bias)[n_blk + col] : bf2f(((const u16*)bias)[n_blk + col]);
#pragma unroll
                for (int mt = 0; mt < 4; mt++){
                    int row0 = wm + mt * 16 + quad * 4;
                    uint2 pk;
                    pk.x = pack_trunc(acc[mt][nt][1] + bv, acc[mt][nt][0] + bv);
                    pk.y = pack_trunc(acc[mt][nt][3] + bv, acc[mt][nt][2] + bv);
                    *(uint2*)&Ct[col * CTS + row0] = pk;
                }
            }
            __syncthreads();
            const int b = m_blk >> 11, t0 = m_blk & 2047;
#pragma unroll
            for (int i = 0; i < 8; i++){
                int u = i * 256 + tid;
                int col = u >> 4, c8 = u & 15;
                int h = hbase + (col >> 6), d = col & 63;
                u16x8 v = *(const u16x8*)&Ct[col * CTS + c8 * 8];
                *(u16x8*)&Cv[(((size_t)(b * 16 + h)) * 64 + d) * 2048 + t0 + c8 * 8] = v;
            }
        }
    } else {
#pragma unroll
        for (int nt = 0; nt < 4; nt++){
            int col = n_blk + wn + nt * 16 + ml;
            float bv = isf32 ? ((const float*)bias)[col] : bf2f(((const u16*)bias)[col]);
#pragma unroll
            for (int mt = 0; mt < 4; mt++){
                float o0 = acc[mt][nt][0] + bv, o1 = acc[mt][nt][1] + bv;
                float o2 = acc[mt][nt][2] + bv, o3 = acc[mt][nt][3] + bv;
                int row0 = m_blk + wm + mt * 16 + quad * 4;
                if (isf32){
                    float* p = (float*)C + (size_t)row0 * N + col;
                    p[0] = o0; p[N] = o1; p[2*N] = o2; p[3*N] = o3;
                } else {
                    u16* p = (u16*)C + (size_t)row0 * N + col;
                    p[0] = f2bf(o0); p[N] = f2bf(o1); p[2*N] = f2bf(o2); p[3*N] = f2bf(o3);
                }
            }
        }
    }
}

// ---------------- flash attention, causal, hd=64, T=2048 ----------------
// R7: T14 reg-staged K/V double-pipeline. Loads for tile j+1 (8x dwordx4/thread,
// 32 VGPR) are issued at the START of compute(j); iteration j+1's first
// __syncthreads' implicit vmcnt(0) is exactly the needed wait (zero extra), then
// 8x ds_write_b128 re-stage into the SAME swizzled LDS layout. HBM latency hides
// under the full QK/softmax/PV phase instead of stalling serially each tile.
#define PS 136
__global__ __launch_bounds__(256) void attn_kernel(
    const u16* __restrict__ Q, const u16* __restrict__ K, const u16* __restrict__ Vt,
    u16* __restrict__ Y)
{
    __shared__ u16 Ksm[128 * 64];        // K[t'][c], chunk c stored at c ^ (t'&7)
    __shared__ u16 Vsm[64 * 128];        // V^T[d][t'], chunk c stored at c ^ (d&15)
    __shared__ u16 Psm[4][32 * PS];      // per-wave P (2 m-tiles x 16 rows), padded

    const int tid = threadIdx.x, wave = tid >> 6, lane = tid & 63;
    const int quad = lane >> 4, ml = lane & 15;
    const int flat = blockIdx.x;
    const int qb = 15 - (flat >> 6);
    const int rest = flat & 63;
    const int bh = ((rest & 7) << 3) | (rest >> 3);
    const int q0 = qb * 128;
    const size_t base = (size_t)bh * (2048 * 64);
    const float NEG = -1.0e30f;

    bf16x8 qf[2][2];
#pragma unroll
    for (int mt = 0; mt < 2; mt++)
#pragma unroll
        for (int ks = 0; ks < 2; ks++)
            qf[mt][ks] = *(const bf16x8*)(Q + base + (size_t)(q0 + mt * 64 + wave * 16 + ml) * 64 + ks * 32 + quad * 8);

    // T14 staging precompute: thread -> 4 K-chunks + 4 V-chunks (swizzled source,
    // linear LDS dest u*16B) — identical layout to the old glds16 path.
    int koff[4], voff[4], udst[4];
#pragma unroll
    for (int i = 0; i < 4; i++){
        int u = i * 256 + tid;
        int row = u >> 3, cg = (tid & 7) ^ (row & 7);
        koff[i] = row * 64 + cg * 8;
        int d = u >> 4, vg = (tid & 15) ^ (d & 15);
        voff[i] = d * 2048 + vg * 8;
        udst[i] = u * 8;
    }
    uint4 kreg[4], vreg[4];
#define LOADKV(J0) { \
    _Pragma("unroll") \
    for (int i = 0; i < 4; i++){ \
        kreg[i] = *(const uint4*)(K  + base + (size_t)(J0) * 64 + koff[i]); \
        vreg[i] = *(const uint4*)(Vt + base + (size_t)(J0) + voff[i]); } }

    f32x4 acc[2][4];
#pragma unroll
    for (int mt = 0; mt < 2; mt++)
#pragma unroll
        for (int nt = 0; nt < 4; nt++) acc[mt][nt] = (f32x4){0.f, 0.f, 0.f, 0.f};
    float l[2][4];
#pragma unroll
    for (int mt = 0; mt < 2; mt++)
#pragma unroll
        for (int r = 0; r < 4; r++) l[mt][r] = 0.f;

    const int ntj = qb + 1;
    LOADKV(0);
    for (int j = 0; j < ntj; j++){
        __syncthreads();                 // prior PV reads done + implicit vmcnt(0) = kreg/vreg ready
#pragma unroll
        for (int i = 0; i < 4; i++){
            *(uint4*)(Ksm + udst[i]) = kreg[i];
            *(uint4*)(Vsm + udst[i]) = vreg[i];
        }
        __syncthreads();                 // ds_writes visible (nothing outstanding on vmcnt)
        if (j + 1 < ntj) LOADKV((j + 1) * 128);   // overlaps the whole compute phase
        const bool lastj = (j == ntj - 1);

        // S = Q@K^T per 16-col tile; exp2 + P write immediately (s regs transient)
#pragma unroll
        for (int nt = 0; nt < 8; nt++){
            bf16x8 bk0 = *(const bf16x8*)&Ksm[(nt * 16 + ml) * 64 + ((quad)     ^ (ml & 7)) * 8];
            bf16x8 bk1 = *(const bf16x8*)&Ksm[(nt * 16 + ml) * 64 + ((4 + quad) ^ (ml & 7)) * 8];
            f32x4 z = {0.f, 0.f, 0.f, 0.f};
            f32x4 s0 = __builtin_amdgcn_mfma_f32_16x16x32_bf16(qf[0][0], bk0, z, 0, 0, 0);
            s0 = __builtin_amdgcn_mfma_f32_16x16x32_bf16(qf[0][1], bk1, s0, 0, 0, 0);
            f32x4 s1 = __builtin_amdgcn_mfma_f32_16x16x32_bf16(qf[1][0], bk0, z, 0, 0, 0);
            s1 = __builtin_amdgcn_mfma_f32_16x16x32_bf16(qf[1][1], bk1, s1, 0, 0, 0);
            if (lastj){
                int cl = nt * 16 + ml;
                int r0 = wave * 16 + quad * 4;
#pragma unroll
                for (int r = 0; r < 4; r++){
                    if (cl > r0 + r)      s0[r] = NEG;
                    if (cl > 64 + r0 + r) s1[r] = NEG;
                }
            }
#pragma unroll
            for (int r = 0; r < 4; r++){
                float p0 = exp2_fast(s0[r]); l[0][r] += p0;
                Psm[wave][(quad * 4 + r) * PS + nt * 16 + ml] = f2bf_t(p0);
                float p1 = exp2_fast(s1[r]); l[1][r] += p1;
                Psm[wave][(16 + quad * 4 + r) * PS + nt * 16 + ml] = f2bf_t(p1);
            }
        }
        // O += P @ V  (vf shared across both m-tiles)
#pragma unroll
        for (int ks = 0; ks < 4; ks++){
            bf16x8 pf0 = *(const bf16x8*)&Psm[wave][ml * PS + ks * 32 + quad * 8];
            bf16x8 pf1 = *(const bf16x8*)&Psm[wave][(16 + ml) * PS + ks * 32 + quad * 8];
#pragma unroll
            for (int nt = 0; nt < 4; nt++){
                bf16x8 vf = *(const bf16x8*)&Vsm[(nt * 16 + ml) * 128 + (((ks * 4 + quad) ^ ml) & 15) * 8];
                acc[0][nt] = __builtin_amdgcn_mfma_f32_16x16x32_bf16(pf0, vf, acc[0][nt], 0, 0, 0);
                acc[1][nt] = __builtin_amdgcn_mfma_f32_16x16x32_bf16(pf1, vf, acc[1][nt], 0, 0, 0);
            }
        }
    }
#undef LOADKV
    // epilogue: l-reduction across the 16 ml lanes, then scale + store
    const int b = bh >> 4, h = bh & 15;
#pragma unroll
    for (int mt = 0; mt < 2; mt++){
        f32x4 inv;
#pragma unroll
        for (int r = 0; r < 4; r++){
            float t = l[mt][r];
            t += __shfl_xor(t, 1, 64);
            t += __shfl_xor(t, 2, 64);
            t += __shfl_xor(t, 4, 64);
            t += __shfl_xor(t, 8, 64);
            inv[r] = 1.0f / t;
        }
#pragma unroll
        for (int nt = 0; nt < 4; nt++)
#pragma unroll
            for (int r = 0; r < 4; r++){
                size_t row = (size_t)b * 2048 + q0 + mt * 64 + wave * 16 + quad * 4 + r;
                Y[row * 1024 + h * 64 + nt * 16 + ml] = f2bf(acc[mt][nt][r] * inv[r]);
            }
    }
}

extern "C" void kernel_launch(void* const* d_in, const int* in_sizes, int n_in,
                              void* d_out, int out_size, void* d_ws, size_t ws_size,
                              hipStream_t stream) {
    const void* x      = d_in[0];   // [8192][1024]  f32 or bf16 (probed at runtime)
    const void* W_attn = d_in[1];   // [1024][3072]
    const void* b_attn = d_in[2];   // [3072]
    const void* W_proj = d_in[3];   // [1024][1024]
    const void* b_proj = d_in[4];   // [1024]
    const u16* xprobe = (const u16*)x;

    // ws layout (64 MB, sequential reuse — verified R4-R7):
    //   [0, 8M)  elems: Q (pre-scaled); reused for Wt_proj after attention
    //   [8M,16M) elems: K
    //   [16M,24M)elems: Vt  [bh][d][t]
    //   [24M,32M)elems: Wt_attn (3M) -> Yw (8M)
    // x-as-bf16 lives in d_out as scratch until the final GEMM.
    u16* ws = (u16*)d_ws;
    u16* Qw = ws;
    u16* Kw = ws + 8u * 1024 * 1024;
    u16* Vw = ws + 16u * 1024 * 1024;
    u16* R  = ws + 24u * 1024 * 1024;
    u16* Wt_attn = R;
    u16* Yw      = R;
    u16* Wt_proj = Qw;
    u16* xb = (u16*)d_out;

    conv_x<<<4096, 256, 0, stream>>>(x, xb, xprobe);
    transposeW<<<dim3(48, 16), 256, 0, stream>>>(W_attn, Wt_attn, 1024, 3072, xprobe);
    gemm128<0><<<dim3(24, 64), 256, 0, stream>>>(
        xb, Wt_attn, b_attn, nullptr, Qw, Kw, Vw, xprobe, 8192, 3072, 1024);
    attn_kernel<<<1024, 256, 0, stream>>>(Qw, Kw, Vw, Yw);
    transposeW<<<dim3(16, 16), 256, 0, stream>>>(W_proj, Wt_proj, 1024, 1024, xprobe);
    gemm128<1><<<dim3(8, 64), 256, 0, stream>>>(
        Yw, Wt_proj, b_proj, d_out, nullptr, nullptr, nullptr, xprobe, 8192, 1024, 1024);
}

// Round 8
// 242.162 us; speedup vs baseline: 1.2017x; 1.2017x over previous
//
#include <hip/hip_runtime.h>

typedef unsigned short u16;
typedef __bf16 bf16x8 __attribute__((ext_vector_type(8)));
typedef float    f32x4 __attribute__((ext_vector_type(4)));
typedef unsigned short u16x8 __attribute__((ext_vector_type(8)));

__device__ __forceinline__ float bf2f(u16 v){ return __uint_as_float(((unsigned int)v) << 16); }
__device__ __forceinline__ u16 f2bf(float f){
    unsigned int u = __float_as_uint(f);
    u += 0x7fffu + ((u >> 16) & 1u);
    return (u16)(u >> 16);
}
// truncating bf16 (~2^-8 rel err, rounds toward zero); selects d16_hi stores
__device__ __forceinline__ u16 f2bf_t(float f){ return (u16)(__float_as_uint(f) >> 16); }
// pack hi16 of two floats: result = [lo.hi16, hi.hi16]
__device__ __forceinline__ unsigned pack_trunc(float hi, float lo){
    return __builtin_amdgcn_perm(__float_as_uint(hi), __float_as_uint(lo), 0x07060302);
}
// raw v_exp_f32 (no libm denorm fixup); x=-1e30 -> 0
__device__ __forceinline__ float exp2_fast(float x){
    float r; asm("v_exp_f32 %0, %1" : "=v"(r) : "v"(x)); return r;
}

// async global->LDS, 16B per lane; LDS dest = wave-uniform base + lane*16.
__device__ __forceinline__ void glds16(const u16* gp, u16* lp){
    __builtin_amdgcn_global_load_lds((unsigned int __attribute__((address_space(1)))*)gp,
                                     (unsigned int __attribute__((address_space(3)))*)lp,
                                     16, 0, 0);
}

// Wave-uniform input-dtype probe (verified R4-R7).
__device__ __forceinline__ int probe_f32(const u16* __restrict__ xp){
    u16 lo = xp[2 * (threadIdx.x & 63)];
    int e = (lo >> 7) & 0xff;
    bool bad = !(e == 0 || (e > 96 && e < 160));
    return __popcll(__ballot(bad)) > 16;
}

// ---------- x -> canonical bf16 (into d_out scratch) ----------
__global__ __launch_bounds__(256) void conv_x(const void* __restrict__ src, u16* __restrict__ dst,
                                              const u16* __restrict__ xprobe){
    const int isf32 = probe_f32(xprobe);
    size_t i = ((size_t)blockIdx.x * 256 + threadIdx.x) * 8;
    if (isf32){
        const float* p = (const float*)src + i;
        float4 a = *(const float4*)p, b = *(const float4*)(p + 4);
        u16x8 o = { f2bf(a.x), f2bf(a.y), f2bf(a.z), f2bf(a.w),
                    f2bf(b.x), f2bf(b.y), f2bf(b.z), f2bf(b.w) };
        *(u16x8*)(dst + i) = o;
    } else {
        *(u16x8*)(dst + i) = *(const u16x8*)((const u16*)src + i);
    }
}

// ---------- transpose+convert: out[C][R](bf16) = in[R][C](f32 or bf16) ----------
__global__ __launch_bounds__(256) void transposeW(const void* __restrict__ in, u16* __restrict__ out,
                                                  int R, int C, const u16* __restrict__ xprobe){
    __shared__ u16 t[64][65];
    const int isf32 = probe_f32(xprobe);
    const int c0 = blockIdx.x * 64, r0 = blockIdx.y * 64;
    const int tx = threadIdx.x & 15, ty = threadIdx.x >> 4;
#pragma unroll
    for (int i = 0; i < 4; i++){
        int r = ty + i * 16;
        u16 a, b, c, d;
        if (isf32){
            float4 v = *(const float4*)((const float*)in + (size_t)(r0 + r) * C + c0 + tx * 4);
            a = f2bf(v.x); b = f2bf(v.y); c = f2bf(v.z); d = f2bf(v.w);
        } else {
            ushort4 v = *(const ushort4*)((const u16*)in + (size_t)(r0 + r) * C + c0 + tx * 4);
            a = v.x; b = v.y; c = v.z; d = v.w;
        }
        t[r][tx*4+0] = a; t[r][tx*4+1] = b; t[r][tx*4+2] = c; t[r][tx*4+3] = d;
    }
    __syncthreads();
#pragma unroll
    for (int i = 0; i < 4; i++){
        int oc = ty + i * 16;
        ushort4 v;
        v.x = t[tx*4+0][oc]; v.y = t[tx*4+1][oc]; v.z = t[tx*4+2][oc]; v.w = t[tx*4+3][oc];
        *(ushort4*)(out + (size_t)(c0 + oc) * R + r0 + tx * 4) = v;
    }
}

// ---------------- GEMM (m97 structure, BK=64): C[M,N] = A[M,K] @ Bt[N,K]^T + bias --------
// 256 threads = 4 waves (2Mx2N), wave tile 64x64, tile 128x128, single-buffered staging.
// Measured-best R5 configuration (67.5 us on QKV):
//  - BK=64 (16 iters, 32 MFMA per drain), LDS union staging|Ct = 34 KiB -> 4 blocks/CU.
//  - bank swizzle on 128B rows: chunk ^= (row&7), pre-swizzled GLOBAL source (rule #21).
//  - T1 bijective XCD swizzle (grid % 8 == 0).
// MODE 0: LDS-restaged epilogue -> coalesced 16B stores to Q(pre-scaled)/K ([bh][t][64])
//         and Vt ([bh][d][2048], V-blocks transposed in LDS).
// MODE 1: C row-major, f32 or bf16 per probe.
#define CTS 136
template<int MODE>
__global__ __launch_bounds__(256) void gemm128(
    const u16* __restrict__ A, const u16* __restrict__ Bt, const void* __restrict__ bias,
    void* __restrict__ C, u16* __restrict__ Cq, u16* __restrict__ Ck, u16* __restrict__ Cv,
    const u16* __restrict__ xprobe, int M, int N, int K)
{
    __shared__ u16 lds[17408];           // union: staging 16384 elems | Ct 128*136
    u16* Asm = lds;                      // [128][64]
    u16* Bsm = lds + 8192;               // [128][64]
    u16* Ct  = lds;                      // epilogue restage (after sync)
    const int isf32 = probe_f32(xprobe);
    const int tid = threadIdx.x;
    const int wave = tid >> 6, lane = tid & 63;
    const int quad = lane >> 4, ml = lane & 15;

    // T1: bijective XCD swizzle (nwg % 8 == 0 for all dispatches)
    const int nbx = gridDim.x;
    int flat = blockIdx.y * nbx + blockIdx.x;
    const int cpx = (nbx * gridDim.y) >> 3;
    flat = (flat & 7) * cpx + (flat >> 3);
    const int m_blk = (flat / nbx) * 128;
    const int n_blk = (flat % nbx) * 128;

    const int wm = (wave >> 1) * 64, wn = (wave & 1) * 64;
    const int srow = lane >> 3;          // 0..7 within the 8-row group
    const int sch  = lane & 7;           // linear dest chunk

    f32x4 acc[4][4];
#pragma unroll
    for (int a = 0; a < 4; a++)
#pragma unroll
        for (int b = 0; b < 4; b++)
            acc[a][b] = (f32x4){0.f, 0.f, 0.f, 0.f};

    for (int k0 = 0; k0 < K; k0 += 64){
        __syncthreads();
#pragma unroll
        for (int i = 0; i < 4; i++){
            int row = wave * 32 + i * 8 + srow;          // 0..127
            int sc  = sch ^ (row & 7);                   // pre-swizzled source chunk
            glds16(A  + (size_t)(m_blk + row) * K + k0 + sc * 8, Asm + (wave * 32 + i * 8) * 64);
            glds16(Bt + (size_t)(n_blk + row) * K + k0 + sc * 8, Bsm + (wave * 32 + i * 8) * 64);
        }
        __syncthreads();
#pragma unroll
        for (int ks = 0; ks < 2; ks++){
            bf16x8 af[4], bfr[4];
#pragma unroll
            for (int mt = 0; mt < 4; mt++)
                af[mt]  = *(const bf16x8*)&Asm[(wm + mt * 16 + ml) * 64 + ((ks * 4 + quad) ^ (ml & 7)) * 8];
#pragma unroll
            for (int nt = 0; nt < 4; nt++)
                bfr[nt] = *(const bf16x8*)&Bsm[(wn + nt * 16 + ml) * 64 + ((ks * 4 + quad) ^ (ml & 7)) * 8];
#pragma unroll
            for (int mt = 0; mt < 4; mt++)
#pragma unroll
                for (int nt = 0; nt < 4; nt++)
                    acc[mt][nt] = __builtin_amdgcn_mfma_f32_16x16x32_bf16(af[mt], bfr[nt], acc[mt][nt], 0, 0, 0);
        }
    }
    __syncthreads();                      // fence: staging LDS -> Ct reuse

    const float QSC = 0.18033688f;   // 0.125 * log2(e) folded into Q
    if (MODE == 0){
        const int which = n_blk >> 10;
        const int hbase = (n_blk >> 6) & 15;
        if (which < 2){
            const float sc = (which == 0) ? QSC : 1.0f;
#pragma unroll
            for (int nt = 0; nt < 4; nt++){
                int col = wn + nt * 16 + ml;
                float bv = isf32 ? ((const float*)bias)[n_blk + col] : bf2f(((const u16*)bias)[n_blk + col]);
#pragma unroll
                for (int mt = 0; mt < 4; mt++){
                    int row0 = wm + mt * 16 + quad * 4;
#pragma unroll
                    for (int r = 0; r < 4; r++)
                        Ct[(row0 + r) * CTS + col] = f2bf_t((acc[mt][nt][r] + bv) * sc);
                }
            }
            __syncthreads();
            u16* dst0 = (which == 0) ? Cq : Ck;
            const int b = m_blk >> 11, t0 = m_blk & 2047;
#pragma unroll
            for (int i = 0; i < 8; i++){
                int u = i * 256 + tid;
                int row = u >> 4, c8 = u & 15;
                int h = hbase + (c8 >> 3), d8 = (c8 & 7) * 8;
                u16x8 v = *(const u16x8*)&Ct[row * CTS + c8 * 8];
                *(u16x8*)&dst0[(((size_t)(b * 16 + h)) * 2048 + (t0 + row)) * 64 + d8] = v;
            }
        } else {
#pragma unroll
            for (int nt = 0; nt < 4; nt++){
                int col = wn + nt * 16 + ml;
                float bv = isf32 ? ((const float*)bias)[n_blk + col] : bf2f(((const u16*)bias)[n_blk + col]);
#pragma unroll
                for (int mt = 0; mt < 4; mt++){
                    int row0 = wm + mt * 16 + quad * 4;
                    uint2 pk;
                    pk.x = pack_trunc(acc[mt][nt][1] + bv, acc[mt][nt][0] + bv);
                    pk.y = pack_trunc(acc[mt][nt][3] + bv, acc[mt][nt][2] + bv);
                    *(uint2*)&Ct[col * CTS + row0] = pk;
                }
            }
            __syncthreads();
            const int b = m_blk >> 11, t0 = m_blk & 2047;
#pragma unroll
            for (int i = 0; i < 8; i++){
                int u = i * 256 + tid;
                int col = u >> 4, c8 = u & 15;
                int h = hbase + (col >> 6), d = col & 63;
                u16x8 v = *(const u16x8*)&Ct[col * CTS + c8 * 8];
                *(u16x8*)&Cv[(((size_t)(b * 16 + h)) * 64 + d) * 2048 + t0 + c8 * 8] = v;
            }
        }
    } else {
#pragma unroll
        for (int nt = 0; nt < 4; nt++){
            int col = n_blk + wn + nt * 16 + ml;
            float bv = isf32 ? ((const float*)bias)[col] : bf2f(((const u16*)bias)[col]);
#pragma unroll
            for (int mt = 0; mt < 4; mt++){
                float o0 = acc[mt][nt][0] + bv, o1 = acc[mt][nt][1] + bv;
                float o2 = acc[mt][nt][2] + bv, o3 = acc[mt][nt][3] + bv;
                int row0 = m_blk + wm + mt * 16 + quad * 4;
                if (isf32){
                    float* p = (float*)C + (size_t)row0 * N + col;
                    p[0] = o0; p[N] = o1; p[2*N] = o2; p[3*N] = o3;
                } else {
                    u16* p = (u16*)C + (size_t)row0 * N + col;
                    p[0] = f2bf(o0); p[N] = f2bf(o1); p[2*N] = f2bf(o2); p[3*N] = f2bf(o3);
                }
            }
        }
    }
}

// ---------------- flash attention, causal, hd=64, T=2048 ----------------
// R8: proven glds16 staging (R5) + SWAPPED QK^T (T12 trick): S = mfma(K, Q) makes each
// lane own 4 CONSECUTIVE k of one q-row (q = wave*16+ml, k = nt*16+quad*4+r), so the
// P scatter is ONE ds_write_b64 of packed bf16 pairs instead of 64 scalar b16 stores
// per tile (-28% LDS issue; kernel is LDS-issue-bound). Psm layout, PV phase, acc
// layout, and Y stores unchanged. l is per-thread row-partial, reduced via
// shfl_xor(16/32) and redistributed by 8 epilogue shfls.
#define PS 136
__global__ __launch_bounds__(256) void attn_kernel(
    const u16* __restrict__ Q, const u16* __restrict__ K, const u16* __restrict__ Vt,
    u16* __restrict__ Y)
{
    __shared__ u16 Ksm[128 * 64];        // K[t'][c], chunk c stored at c ^ (t'&7)
    __shared__ u16 Vsm[64 * 128];        // V^T[d][t'], chunk c stored at c ^ (d&15)
    __shared__ u16 Psm[4][32 * PS];      // per-wave P (2 m-tiles x 16 rows), padded

    const int tid = threadIdx.x, wave = tid >> 6, lane = tid & 63;
    const int quad = lane >> 4, ml = lane & 15;
    const int flat = blockIdx.x;
    const int qb = 15 - (flat >> 6);
    const int rest = flat & 63;
    const int bh = ((rest & 7) << 3) | (rest >> 3);
    const int q0 = qb * 128;
    const size_t base = (size_t)bh * (2048 * 64);
    const float NEG = -1.0e30f;

    bf16x8 qf[2][2];
#pragma unroll
    for (int mt = 0; mt < 2; mt++)
#pragma unroll
        for (int ks = 0; ks < 2; ks++)
            qf[mt][ks] = *(const bf16x8*)(Q + base + (size_t)(q0 + mt * 64 + wave * 16 + ml) * 64 + ks * 32 + quad * 8);

    f32x4 acc[2][4];
#pragma unroll
    for (int mt = 0; mt < 2; mt++)
#pragma unroll
        for (int nt = 0; nt < 4; nt++) acc[mt][nt] = (f32x4){0.f, 0.f, 0.f, 0.f};
    float l0 = 0.f, l1 = 0.f;            // row-partials for q = wave*16+ml (+64)

    const int qme = wave * 16 + ml;      // this lane's q-row within the 128-row tile
    const int ntj = qb + 1;
    for (int j = 0; j < ntj; j++){
        const int j0 = j * 128;
        __syncthreads();
#pragma unroll
        for (int i = 0; i < 4; i++){
            int ub = i * 256 + wave * 64;
            int u = ub + lane;
            int row = u >> 3, cg = (lane & 7) ^ (row & 7);
            glds16(K + base + (size_t)(j0 + row) * 64 + cg * 8, Ksm + ub * 8);
            int d = u >> 4, vg = (lane & 15) ^ (d & 15);
            glds16(Vt + base + (size_t)d * 2048 + j0 + vg * 8, Vsm + ub * 8);
        }
        __syncthreads();
        const bool lastj = (j == ntj - 1);

        // S^T = K@Q^T per 16-row k-tile (swapped operands); lane holds
        // s[r] = S[q = wave*16+ml][k = nt*16+quad*4+r] -> packed b64 P write.
#pragma unroll
        for (int nt = 0; nt < 8; nt++){
            bf16x8 bk0 = *(const bf16x8*)&Ksm[(nt * 16 + ml) * 64 + ((quad)     ^ (ml & 7)) * 8];
            bf16x8 bk1 = *(const bf16x8*)&Ksm[(nt * 16 + ml) * 64 + ((4 + quad) ^ (ml & 7)) * 8];
            f32x4 z = {0.f, 0.f, 0.f, 0.f};
            f32x4 s0 = __builtin_amdgcn_mfma_f32_16x16x32_bf16(bk0, qf[0][0], z, 0, 0, 0);
            s0 = __builtin_amdgcn_mfma_f32_16x16x32_bf16(bk1, qf[0][1], s0, 0, 0, 0);
            f32x4 s1 = __builtin_amdgcn_mfma_f32_16x16x32_bf16(bk0, qf[1][0], z, 0, 0, 0);
            s1 = __builtin_amdgcn_mfma_f32_16x16x32_bf16(bk1, qf[1][1], s1, 0, 0, 0);
            if (lastj){
                int cl = nt * 16 + quad * 4;
#pragma unroll
                for (int r = 0; r < 4; r++){
                    if (cl + r > qme)      s0[r] = NEG;
                    if (cl + r > 64 + qme) s1[r] = NEG;
                }
            }
            float a0 = exp2_fast(s0[0]), a1 = exp2_fast(s0[1]);
            float a2 = exp2_fast(s0[2]), a3 = exp2_fast(s0[3]);
            l0 += (a0 + a1) + (a2 + a3);
            uint2 pk0; pk0.x = pack_trunc(a1, a0); pk0.y = pack_trunc(a3, a2);
            *(uint2*)&Psm[wave][ml * PS + nt * 16 + quad * 4] = pk0;
            float b0 = exp2_fast(s1[0]), b1 = exp2_fast(s1[1]);
            float b2 = exp2_fast(s1[2]), b3 = exp2_fast(s1[3]);
            l1 += (b0 + b1) + (b2 + b3);
            uint2 pk1; pk1.x = pack_trunc(b1, b0); pk1.y = pack_trunc(b3, b2);
            *(uint2*)&Psm[wave][(16 + ml) * PS + nt * 16 + quad * 4] = pk1;
        }
        // O += P @ V  (vf shared across both m-tiles) — unchanged
#pragma unroll
        for (int ks = 0; ks < 4; ks++){
            bf16x8 pf0 = *(const bf16x8*)&Psm[wave][ml * PS + ks * 32 + quad * 8];
            bf16x8 pf1 = *(const bf16x8*)&Psm[wave][(16 + ml) * PS + ks * 32 + quad * 8];
#pragma unroll
            for (int nt = 0; nt < 4; nt++){
                bf16x8 vf = *(const bf16x8*)&Vsm[(nt * 16 + ml) * 128 + (((ks * 4 + quad) ^ ml) & 15) * 8];
                acc[0][nt] = __builtin_amdgcn_mfma_f32_16x16x32_bf16(pf0, vf, acc[0][nt], 0, 0, 0);
                acc[1][nt] = __builtin_amdgcn_mfma_f32_16x16x32_bf16(pf1, vf, acc[1][nt], 0, 0, 0);
            }
        }
    }
    // epilogue: quad-reduce the row-partials, redistribute 1/l to the acc layout, store
    const int b = bh >> 4, h = bh & 15;
    l0 += __shfl_xor(l0, 16, 64);  l0 += __shfl_xor(l0, 32, 64);
    l1 += __shfl_xor(l1, 16, 64);  l1 += __shfl_xor(l1, 32, 64);
    float rl0 = 1.0f / l0, rl1 = 1.0f / l1;
    f32x4 inv[2];
#pragma unroll
    for (int r = 0; r < 4; r++){
        inv[0][r] = __shfl(rl0, quad * 4 + r, 64);   // lane with ml == quad*4+r (quad 0)
        inv[1][r] = __shfl(rl1, quad * 4 + r, 64);
    }
#pragma unroll
    for (int mt = 0; mt < 2; mt++)
#pragma unroll
        for (int nt = 0; nt < 4; nt++)
#pragma unroll
            for (int r = 0; r < 4; r++){
                size_t row = (size_t)b * 2048 + q0 + mt * 64 + wave * 16 + quad * 4 + r;
                Y[row * 1024 + h * 64 + nt * 16 + ml] = f2bf(acc[mt][nt][r] * inv[mt][r]);
            }
}

extern "C" void kernel_launch(void* const* d_in, const int* in_sizes, int n_in,
                              void* d_out, int out_size, void* d_ws, size_t ws_size,
                              hipStream_t stream) {
    const void* x      = d_in[0];   // [8192][1024]  f32 or bf16 (probed at runtime)
    const void* W_attn = d_in[1];   // [1024][3072]
    const void* b_attn = d_in[2];   // [3072]
    const void* W_proj = d_in[3];   // [1024][1024]
    const void* b_proj = d_in[4];   // [1024]
    const u16* xprobe = (const u16*)x;

    // ws layout (64 MB, sequential reuse — verified R4-R7):
    //   [0, 8M)  elems: Q (pre-scaled); reused for Wt_proj after attention
    //   [8M,16M) elems: K
    //   [16M,24M)elems: Vt  [bh][d][t]
    //   [24M,32M)elems: Wt_attn (3M) -> Yw (8M)
    // x-as-bf16 lives in d_out as scratch until the final GEMM.
    u16* ws = (u16*)d_ws;
    u16* Qw = ws;
    u16* Kw = ws + 8u * 1024 * 1024;
    u16* Vw = ws + 16u * 1024 * 1024;
    u16* R  = ws + 24u * 1024 * 1024;
    u16* Wt_attn = R;
    u16* Yw      = R;
    u16* Wt_proj = Qw;
    u16* xb = (u16*)d_out;

    conv_x<<<4096, 256, 0, stream>>>(x, xb, xprobe);
    transposeW<<<dim3(48, 16), 256, 0, stream>>>(W_attn, Wt_attn, 1024, 3072, xprobe);
    gemm128<0><<<dim3(24, 64), 256, 0, stream>>>(
        xb, Wt_attn, b_attn, nullptr, Qw, Kw, Vw, xprobe, 8192, 3072, 1024);
    attn_kernel<<<1024, 256, 0, stream>>>(Qw, Kw, Vw, Yw);
    transposeW<<<dim3(16, 16), 256, 0, stream>>>(W_proj, Wt_proj, 1024, 1024, xprobe);
    gemm128<1><<<dim3(8, 64), 256, 0, stream>>>(
        Yw, Wt_proj, b_proj, d_out, nullptr, nullptr, nullptr, xprobe, 8192, 1024, 1024);
}